// Round 11
// baseline (1137.561 us; speedup 1.0000x reference)
//
#include <hip/hip_runtime.h>
#include <hip/hip_bf16.h>
#include <hip/hip_fp16.h>

// Problem constants (from the reference)
constexpr int NU = 80000;    // users
constexpr int NI = 40000;    // items
constexpr int K  = 64;       // feature dim (== wavefront size, 1 lane per k)
constexpr int NL = 3;        // layers
constexpr int NN = NU + NI;  // 120000 nodes
constexpr int NE = 1000000;  // edges (undirected; each contributes both dirs)
constexpr float EPS   = 1e-12f;
constexpr float SLOPE = 0.01f;

constexpr int SCAN_B = 256;
constexpr int NBLK   = (NN + SCAN_B - 1) / SCAN_B;   // 469 scan blocks

// Bucketed CSR fill: bucket = row >> 7 (128 rows/bucket)
constexpr int BSH     = 7;
constexpr int NB_BUCK = (NN + (1 << BSH) - 1) >> BSH;   // 938 buckets

// broadcast lane l's value to all lanes via v_readlane -> SGPR operand
__device__ __forceinline__ float bcast(float v, int l) {
    return __uint_as_float(__builtin_amdgcn_readlane(__float_as_uint(v), l));
}

// ---------------------------------------------------------------------------
// Kernel 1: e0 = l2norm(concat(Gu, Gi)) stored fp16; gsum[n] = rowsum(e0)
// ---------------------------------------------------------------------------
__global__ __launch_bounds__(256)
void norm_init_kernel(const float* __restrict__ Gu, const float* __restrict__ Gi,
                      __half* __restrict__ e, float* __restrict__ gsum) {
    int node = blockIdx.x * 4 + (threadIdx.x >> 6);
    int lane = threadIdx.x & 63;
    if (node >= NN) return;
    float v = (node < NU) ? Gu[node * K + lane] : Gi[(node - NU) * K + lane];
    float ss = v * v;
    #pragma unroll
    for (int off = 32; off > 0; off >>= 1) ss += __shfl_xor(ss, off);
    float r = v / fmaxf(sqrtf(ss), EPS);
    e[(size_t)node * K + lane] = __float2half(r);
    float rs = r;
    #pragma unroll
    for (int off = 32; off > 0; off >>= 1) rs += __shfl_xor(rs, off);
    if (lane == 0) gsum[node] = rs;   // overwrite poison
}

// ---------------------------------------------------------------------------
// CSR build: histogram -> hierarchical exclusive scan -> bucketed 2-pass fill
// ---------------------------------------------------------------------------
__global__ __launch_bounds__(256)
void hist_kernel(const int* __restrict__ eu, const int* __restrict__ ei,
                 int* __restrict__ rowptr) {
    int e = blockIdx.x * blockDim.x + threadIdx.x;
    if (e >= NE) return;
    atomicAdd(&rowptr[1 + eu[e]], 1);
    atomicAdd(&rowptr[1 + ei[e]], 1);
}

__global__ __launch_bounds__(SCAN_B)
void scan1_kernel(int* __restrict__ cnt, int* __restrict__ bsum) {
    __shared__ int sh[SCAN_B];
    int i = blockIdx.x * SCAN_B + threadIdx.x;
    int v = (i < NN) ? cnt[i] : 0;
    sh[threadIdx.x] = v;
    __syncthreads();
    #pragma unroll
    for (int off = 1; off < SCAN_B; off <<= 1) {
        int t = (threadIdx.x >= off) ? sh[threadIdx.x - off] : 0;
        __syncthreads();
        sh[threadIdx.x] += t;
        __syncthreads();
    }
    if (i < NN) cnt[i] = sh[threadIdx.x];
    if (threadIdx.x == SCAN_B - 1) bsum[blockIdx.x] = sh[SCAN_B - 1];
}

__global__ __launch_bounds__(512)
void scan2_kernel(int* __restrict__ bsum) {
    __shared__ int sh[512];
    int v = (threadIdx.x < NBLK) ? bsum[threadIdx.x] : 0;
    sh[threadIdx.x] = v;
    __syncthreads();
    #pragma unroll
    for (int off = 1; off < 512; off <<= 1) {
        int t = (threadIdx.x >= off) ? sh[threadIdx.x - off] : 0;
        __syncthreads();
        sh[threadIdx.x] += t;
        __syncthreads();
    }
    if (threadIdx.x < NBLK) bsum[threadIdx.x] = sh[threadIdx.x] - v; // exclusive
}

__global__ __launch_bounds__(SCAN_B)
void scan3_kernel(int* __restrict__ rowptr, const int* __restrict__ bsum,
                  int* __restrict__ cursor) {
    int i = blockIdx.x * SCAN_B + threadIdx.x;   // index into cnt = rowptr+1
    if (i < NN) {
        int v = rowptr[1 + i] + bsum[blockIdx.x];
        rowptr[1 + i] = v;                        // rowptr[i+1] final
        if (i + 1 < NN) cursor[i + 1] = v;        // start of node i+1
    }
    if (i == 0) cursor[0] = 0;
}

// bucket cursors start at the bucket's cols-region base: rowptr[b*128]
__global__ __launch_bounds__(256)
void bcur_init_kernel(const int* __restrict__ rowptr, int* __restrict__ bcur) {
    int b = blockIdx.x * blockDim.x + threadIdx.x;
    if (b < NB_BUCK) bcur[b] = rowptr[b << BSH];
}

// P1: scatter entries bucket-compacted. Entry (row,col) -> bucket row>>7,
// packed u32 = (row&127)<<17 | col  (col < 2^17). Writes within a bucket are
// cursor-adjacent -> L2 lines absorb ~16 entries each (vs 1 for direct fill).
__global__ __launch_bounds__(256)
void fill_p1_kernel(const int* __restrict__ eu, const int* __restrict__ ei,
                    int* __restrict__ bcur, unsigned* __restrict__ staging) {
    int e = blockIdx.x * blockDim.x + threadIdx.x;
    if (e >= NE) return;
    int u = eu[e];
    int i = ei[e];
    int pu = atomicAdd(&bcur[u >> BSH], 1);
    staging[pu] = ((unsigned)(u & 127) << 17) | (unsigned)i;
    int pi = atomicAdd(&bcur[i >> BSH], 1);
    staging[pi] = ((unsigned)(i & 127) << 17) | (unsigned)u;
}

// P2: one block per bucket; re-scatter staged entries to exact CSR slots.
// Destination region is ~8.5 KB -> L2-resident, write amplification ~1.
__global__ __launch_bounds__(256)
void fill_p2_kernel(const int* __restrict__ rowptr, const unsigned* __restrict__ staging,
                    int* __restrict__ cursor, int* __restrict__ cols) {
    int rbase = blockIdx.x << BSH;
    int s = rowptr[rbase];
    int rend = rbase + (1 << BSH);
    int e = rowptr[rend < NN ? rend : NN];
    for (int t = s + threadIdx.x; t < e; t += 256) {
        unsigned pk = staging[t];
        int row = rbase + (int)(pk >> 17);
        int col = (int)(pk & 0x1FFFFu);
        int pos = atomicAdd(&cursor[row], 1);
        cols[pos] = col;
    }
}

// ---------------------------------------------------------------------------
// Gather SpMM, half-wave-per-node: each lane loads __half2 (2 features), so
// 32 lanes cover a 128B fp16 row and each wave gathers TWO nodes with 4-deep
// unroll = 8 outstanding row-fetches/wave (2x in-flight vs f32 full-wave;
// attacks the latency-bound regime the R9 fp16-null exposed).
// ---------------------------------------------------------------------------
__global__ __launch_bounds__(256)
void gather_kernel(const int* __restrict__ rowptr, const int* __restrict__ cols,
                   const __half* __restrict__ x, float* __restrict__ side) {
    int node = blockIdx.x * 8 + (threadIdx.x >> 5);   // 8 half-waves/block
    int sub  = threadIdx.x & 31;                      // feature-pair index
    if (node >= NN) return;
    const __half2* xp = (const __half2*)x;            // row n = xp[n*32 ...]
    int s = rowptr[node];
    int e = rowptr[node + 1];
    float ax0 = 0.f, ay0 = 0.f, ax1 = 0.f, ay1 = 0.f;
    float ax2 = 0.f, ay2 = 0.f, ax3 = 0.f, ay3 = 0.f;
    int t = s;
    for (; t + 4 <= e; t += 4) {
        int n0 = cols[t];
        int n1 = cols[t + 1];
        int n2 = cols[t + 2];
        int n3 = cols[t + 3];
        float2 v0 = __half22float2(xp[(size_t)n0 * 32 + sub]);
        float2 v1 = __half22float2(xp[(size_t)n1 * 32 + sub]);
        float2 v2 = __half22float2(xp[(size_t)n2 * 32 + sub]);
        float2 v3 = __half22float2(xp[(size_t)n3 * 32 + sub]);
        ax0 += v0.x; ay0 += v0.y;
        ax1 += v1.x; ay1 += v1.y;
        ax2 += v2.x; ay2 += v2.y;
        ax3 += v3.x; ay3 += v3.y;
    }
    for (; t < e; ++t) {
        float2 v = __half22float2(xp[(size_t)cols[t] * 32 + sub]);
        ax0 += v.x; ay0 += v.y;
    }
    float2 r;
    r.x = (ax0 + ax1) + (ax2 + ax3);
    r.y = (ay0 + ay1) + (ay2 + ay3);
    ((float2*)side)[(size_t)node * 32 + sub] = r;
}

// ---------------------------------------------------------------------------
// Dense layer, register-GEMV v2 (fp16 x in, fp16 y out, f32 compute):
//   p = side + x ; q = side * x
//   h = p@W1 + b1 + q@W2 + b2 ; y = l2norm(leaky_relu(h)) ; gsum += rowsum(y)
// ---------------------------------------------------------------------------
__global__ __launch_bounds__(256)
void layer_kernel(const __half* __restrict__ x, const float* __restrict__ side,
                  const float* __restrict__ W1, const float* __restrict__ b1,
                  const float* __restrict__ W2, const float* __restrict__ b2,
                  __half* __restrict__ y, float* __restrict__ gsum) {
    const int wave = threadIdx.x >> 6;
    const int lane = threadIdx.x & 63;

    float w1c[K], w2c[K];
    #pragma unroll
    for (int j = 0; j < K; ++j) {
        w1c[j] = W1[j * K + lane];
        w2c[j] = W2[j * K + lane];
    }
    const float bias = b1[lane] + b2[lane];

    for (int node = blockIdx.x * 4 + wave; node < NN; node += gridDim.x * 4) {
        float xv = __half2float(x[(size_t)node * K + lane]);
        float sv = side[(size_t)node * K + lane];
        float p = sv + xv;
        float q = sv * xv;
        float acc0 = bias, acc1 = 0.f, acc2 = 0.f, acc3 = 0.f;
        #pragma unroll
        for (int j = 0; j < K; j += 4) {
            acc0 = fmaf(bcast(p, j + 0), w1c[j + 0], acc0);
            acc0 = fmaf(bcast(q, j + 0), w2c[j + 0], acc0);
            acc1 = fmaf(bcast(p, j + 1), w1c[j + 1], acc1);
            acc1 = fmaf(bcast(q, j + 1), w2c[j + 1], acc1);
            acc2 = fmaf(bcast(p, j + 2), w1c[j + 2], acc2);
            acc2 = fmaf(bcast(q, j + 2), w2c[j + 2], acc2);
            acc3 = fmaf(bcast(p, j + 3), w1c[j + 3], acc3);
            acc3 = fmaf(bcast(q, j + 3), w2c[j + 3], acc3);
        }
        float acc = (acc0 + acc1) + (acc2 + acc3);

        float h = (acc > 0.f) ? acc : SLOPE * acc;
        float ss = h * h;
        #pragma unroll
        for (int off = 32; off > 0; off >>= 1) ss += __shfl_xor(ss, off);
        float r = h / fmaxf(sqrtf(ss), EPS);
        y[(size_t)node * K + lane] = __float2half(r);
        float rs = r;
        #pragma unroll
        for (int off = 32; off > 0; off >>= 1) rs += __shfl_xor(rs, off);
        if (lane == 0) gsum[node] += rs;   // one wave per node: no race
    }
}

// ---------------------------------------------------------------------------
// out[n] = gsum[n] / ((L+1)*K) = gsum[n] / 256
// ---------------------------------------------------------------------------
__global__ __launch_bounds__(256)
void finalize_kernel(const float* __restrict__ gsum, float* __restrict__ out) {
    int n = blockIdx.x * blockDim.x + threadIdx.x;
    if (n < NN) out[n] = gsum[n] * (1.0f / ((NL + 1) * K));
}

extern "C" void kernel_launch(void* const* d_in, const int* in_sizes, int n_in,
                              void* d_out, int out_size, void* d_ws, size_t ws_size,
                              hipStream_t stream) {
    const float* Gu = (const float*)d_in[0];
    const float* Gi = (const float*)d_in[1];
    const float* W1 = (const float*)d_in[2];   // [NL][K][K]
    const float* b1 = (const float*)d_in[3];   // [NL][K]
    const float* W2 = (const float*)d_in[4];
    const float* b2 = (const float*)d_in[5];
    const int*  edge = (const int*)d_in[6];    // [2][NE]
    float* out = (float*)d_out;

    // Workspace: xbuf0(h) | xbuf1(h) | side(f32) | gsum | rowptr | bsum |
    //            cursor | cols | staging(u32) | bcur       (~79.3 MB)
    __half*   xbuf0   = (__half*)d_ws;
    __half*   xbuf1   = xbuf0 + (size_t)NN * K;
    float*    side    = (float*)(xbuf1 + (size_t)NN * K);
    float*    gsum    = side + (size_t)NN * K;
    int*      rowptr  = (int*)(gsum + NN);
    int*      bsum    = rowptr + (NN + 1);
    int*      cursor  = bsum + 512;
    int*      cols    = cursor + NN;
    unsigned* staging = (unsigned*)(cols + 2 * NE);
    int*      bcur    = (int*)(staging + 2 * NE);

    const int* eu = edge;
    const int* ei = edge + NE;

    // --- CSR build (once per launch) ---
    hipMemsetAsync(rowptr, 0, (size_t)(NN + 1) * sizeof(int), stream);
    hist_kernel <<<(NE + 255) / 256, 256, 0, stream>>>(eu, ei, rowptr);
    scan1_kernel<<<NBLK, SCAN_B, 0, stream>>>(rowptr + 1, bsum);
    scan2_kernel<<<1, 512, 0, stream>>>(bsum);
    scan3_kernel<<<NBLK, SCAN_B, 0, stream>>>(rowptr, bsum, cursor);
    bcur_init_kernel<<<(NB_BUCK + 255) / 256, 256, 0, stream>>>(rowptr, bcur);
    fill_p1_kernel<<<(NE + 255) / 256, 256, 0, stream>>>(eu, ei, bcur, staging);
    fill_p2_kernel<<<NB_BUCK, 256, 0, stream>>>(rowptr, staging, cursor, cols);

    // --- embeddings ---
    norm_init_kernel<<<(NN + 3) / 4, 256, 0, stream>>>(Gu, Gi, xbuf0, gsum);

    __half* cur = xbuf0;
    __half* nxt = xbuf1;
    for (int l = 0; l < NL; ++l) {
        gather_kernel<<<(NN + 7) / 8, 256, 0, stream>>>(rowptr, cols, cur, side);
        layer_kernel<<<1024, 256, 0, stream>>>(cur, side,
                                               W1 + (size_t)l * K * K, b1 + (size_t)l * K,
                                               W2 + (size_t)l * K * K, b2 + (size_t)l * K,
                                               nxt, gsum);
        __half* t = cur; cur = nxt; nxt = t;
    }

    finalize_kernel<<<(NN + 255) / 256, 256, 0, stream>>>(gsum, out);
}